// Round 2
// baseline (23.708 us; speedup 1.0000x reference)
//
#include <hip/hip_runtime.h>

#define R_ROWS   128
#define HALO     16
#define NTHREADS 1024
#define NWAVES   (NTHREADS / 64)

// Wave-parallel lower_bound: first p in [0,n] with idx[p] >= target.
// All 64 lanes participate; returns the same value in every lane.
__device__ __forceinline__ int wave_lower_bound(const int* __restrict__ idx,
                                                int n, int target, int lane) {
    int lo = 0, hi = n;                 // invariant: lo <= ans <= hi
    while (hi - lo > 64) {
        long long span = hi - lo;
        int pos = lo + (int)(span * (long long)(lane + 1) / 65);  // strictly interior
        int v = idx[pos];
        unsigned long long m = __ballot(v >= target);
        if (m == 0ULL) {
            lo = lo + (int)(span * 64LL / 65) + 1;      // all probes < target
        } else {
            int f = (int)__ffsll((unsigned long long)m) - 1;  // first lane with v >= target
            int nhi = lo + (int)(span * (long long)(f + 1) / 65);
            int nlo = (f == 0) ? lo : (lo + (int)(span * (long long)f / 65) + 1);
            hi = nhi; lo = nlo;
        }
    }
    int p = lo + lane;
    int v = (p < hi) ? idx[p] : 0x7fffffff;
    unsigned long long m = __ballot(v >= target);
    return m ? (lo + (int)__ffsll((unsigned long long)m) - 1) : hi;
}

// Fully fused: per block of 128 rows,
//   phase 1: proj_i rows [r0, r0+128), proj_j rows [r0-16, r0+144) -> LDS
//   phase 2: gather the block's contiguous pair range (binary search on idx_i)
// Valid because windows never span >16 rows: any pair with i in this block
// has j within [i-15, i+15] -> inside the haloed proj_j range.
__global__ __launch_bounds__(NTHREADS) void fused_senshift_kernel(
    const float* __restrict__ embeds,
    const float* __restrict__ embeds_temp,
    const float* __restrict__ weight,   // (2, 512) row-major
    const float* __restrict__ bias,     // (2,)
    const int*   __restrict__ idx_i,
    const int*   __restrict__ idx_j,
    float* __restrict__ out,            // (npairs, 2)
    int n, int npairs)
{
    __shared__ float2 s_pi[R_ROWS];
    __shared__ float2 s_pj[R_ROWS + 2 * HALO];
    __shared__ int s_range[2];

    const int tid  = (int)threadIdx.x;
    const int wv   = tid >> 6;
    const int lane = tid & 63;
    const int r0   = (int)blockIdx.x * R_ROWS;
    const int hr0  = r0 - HALO;

    // Per-lane weight fragments, held in registers for all rows.
    const float4 wi0 = *(const float4*)(weight +   0 + lane * 4);
    const float4 wj0 = *(const float4*)(weight + 256 + lane * 4);
    const float4 wi1 = *(const float4*)(weight + 512 + lane * 4);
    const float4 wj1 = *(const float4*)(weight + 768 + lane * 4);

    // Wave 0 finds this block's pair range while other waves start proj.
    if (wv == 0) {
        int plo = wave_lower_bound(idx_i, npairs, r0, lane);
        int phi = wave_lower_bound(idx_i, npairs, r0 + R_ROWS, lane);
        if (lane == 0) { s_range[0] = plo; s_range[1] = phi; }
    }

    // proj_i for rows [r0, r0+R_ROWS)
    #pragma unroll 2
    for (int r = wv; r < R_ROWS; r += NWAVES) {
        const int row = r0 + r;
        if (row >= n) break;                       // wave-uniform
        const float4 e = *(const float4*)(embeds + (size_t)row * 256 + lane * 4);
        float p0 = e.x * wi0.x + e.y * wi0.y + e.z * wi0.z + e.w * wi0.w;
        float p1 = e.x * wi1.x + e.y * wi1.y + e.z * wi1.z + e.w * wi1.w;
        #pragma unroll
        for (int m = 32; m >= 1; m >>= 1) {
            p0 += __shfl_xor(p0, m);
            p1 += __shfl_xor(p1, m);
        }
        if (lane == 0) s_pi[r] = make_float2(p0, p1);
    }

    // proj_j for rows [r0-HALO, r0+R_ROWS+HALO)
    #pragma unroll 2
    for (int r = wv; r < R_ROWS + 2 * HALO; r += NWAVES) {
        const int row = hr0 + r;
        if (row < 0 || row >= n) continue;         // wave-uniform
        const float4 e = *(const float4*)(embeds_temp + (size_t)row * 256 + lane * 4);
        float p0 = e.x * wj0.x + e.y * wj0.y + e.z * wj0.z + e.w * wj0.w;
        float p1 = e.x * wj1.x + e.y * wj1.y + e.z * wj1.z + e.w * wj1.w;
        #pragma unroll
        for (int m = 32; m >= 1; m >>= 1) {
            p0 += __shfl_xor(p0, m);
            p1 += __shfl_xor(p1, m);
        }
        if (lane == 0) s_pj[r] = make_float2(p0, p1);
    }

    __syncthreads();

    // Gather this block's contiguous pair slice.
    const float b0 = bias[0], b1 = bias[1];
    const int plo = s_range[0], phi = s_range[1];
    for (int p = plo + tid; p < phi; p += NTHREADS) {
        const int i = idx_i[p];
        const int j = idx_j[p];
        const float2 a = s_pi[i - r0];
        const float2 c = s_pj[j - hr0];
        *(float2*)(out + 2 * (size_t)p) = make_float2(a.x + c.x + b0,
                                                      a.y + c.y + b1);
    }
}

extern "C" void kernel_launch(void* const* d_in, const int* in_sizes, int n_in,
                              void* d_out, int out_size, void* d_ws, size_t ws_size,
                              hipStream_t stream) {
    const float* embeds      = (const float*)d_in[0];
    const float* embeds_temp = (const float*)d_in[1];
    const float* weight      = (const float*)d_in[2];
    const float* bias        = (const float*)d_in[3];
    const int*   idx_i       = (const int*)d_in[4];
    const int*   idx_j       = (const int*)d_in[5];
    float* out = (float*)d_out;

    const int n      = in_sizes[0] / 256;   // rows
    const int npairs = in_sizes[4];         // pairs

    dim3 grid((n + R_ROWS - 1) / R_ROWS);   // 256 blocks for n=32768
    fused_senshift_kernel<<<grid, NTHREADS, 0, stream>>>(
        embeds, embeds_temp, weight, bias, idx_i, idx_j, out, n, npairs);
}

// Round 3
// 22.660 us; speedup vs baseline: 1.0462x; 1.0462x over previous
//
#include <hip/hip_runtime.h>

#define R_ROWS   64
#define HALO     16
#define PJ_ROWS  (R_ROWS + 2 * HALO)   // 96
#define NTHREADS 512
#define NWAVES   (NTHREADS / 64)       // 8

// Wave-parallel lower_bound: first p in [0,n] with idx[p] >= target.
__device__ __forceinline__ int wave_lower_bound(const int* __restrict__ idx,
                                                int n, int target, int lane) {
    int lo = 0, hi = n;
    while (hi - lo > 64) {
        long long span = hi - lo;
        int pos = lo + (int)(span * (long long)(lane + 1) / 65);
        int v = idx[pos];
        unsigned long long m = __ballot(v >= target);
        if (m == 0ULL) {
            lo = lo + (int)(span * 64LL / 65) + 1;
        } else {
            int f = (int)__ffsll((unsigned long long)m) - 1;
            int nhi = lo + (int)(span * (long long)(f + 1) / 65);
            int nlo = (f == 0) ? lo : (lo + (int)(span * (long long)f / 65) + 1);
            hi = nhi; lo = nlo;
        }
    }
    int p = lo + lane;
    int v = (p < hi) ? idx[p] : 0x7fffffff;
    unsigned long long m = __ballot(v >= target);
    return m ? (lo + (int)__ffsll((unsigned long long)m) - 1) : hi;
}

// Fused: block owns 64 rows. proj via 16-lanes-per-row (4 rows per wave-pass,
// 4-step shfl reduce shared across the 4 row groups). proj_j haloed +-16.
// Gather: contiguous pair slice found by binary search on idx_i.
__global__ __launch_bounds__(NTHREADS, 4) void fused_senshift_kernel(
    const float* __restrict__ embeds,
    const float* __restrict__ embeds_temp,
    const float* __restrict__ weight,   // (2, 512) row-major
    const float* __restrict__ bias,     // (2,)
    const int*   __restrict__ idx_i,
    const int*   __restrict__ idx_j,
    float* __restrict__ out,            // (npairs, 2)
    int n, int npairs)
{
    __shared__ float2 s_pi[R_ROWS];
    __shared__ float2 s_pj[PJ_ROWS];
    __shared__ int s_range[2];

    const int tid  = (int)threadIdx.x;
    const int wv   = tid >> 6;
    const int lane = tid & 63;
    const int sub  = lane & 15;   // lane within 16-lane row group
    const int g    = lane >> 4;   // row group 0..3 within wave
    const int r0   = (int)blockIdx.x * R_ROWS;
    const int hr0  = r0 - HALO;

    // Per-lane weight slices: for chunk c, this lane owns floats
    // (c*16 + sub)*4 .. +3 of each 256-wide weight row. 16 float4 = 64 VGPR.
    float4 wi0[4], wi1[4], wj0[4], wj1[4];
    #pragma unroll
    for (int c = 0; c < 4; ++c) {
        const int off = (c * 16 + sub) * 4;
        wi0[c] = *(const float4*)(weight +   0 + off);
        wj0[c] = *(const float4*)(weight + 256 + off);
        wi1[c] = *(const float4*)(weight + 512 + off);
        wj1[c] = *(const float4*)(weight + 768 + off);
    }

    // Last wave finds the pair range while the others start projecting.
    if (wv == NWAVES - 1) {
        int plo = wave_lower_bound(idx_i, npairs, r0, lane);
        int phi = wave_lower_bound(idx_i, npairs, r0 + R_ROWS, lane);
        if (lane == 0) { s_range[0] = plo; s_range[1] = phi; }
    }

    // proj_i: rows [r0, r0+64). 8 waves x 4 rows = 32 rows per pass, 2 passes.
    for (int base = wv * 4; base < R_ROWS; base += NWAVES * 4) {
        const int r = base + g;
        const int row = r0 + r;
        if (row < n) {
            const float* ep = embeds + (size_t)row * 256;
            float p0 = 0.f, p1 = 0.f;
            #pragma unroll
            for (int c = 0; c < 4; ++c) {
                const float4 e = *(const float4*)(ep + (c * 16 + sub) * 4);
                p0 += e.x * wi0[c].x + e.y * wi0[c].y + e.z * wi0[c].z + e.w * wi0[c].w;
                p1 += e.x * wi1[c].x + e.y * wi1[c].y + e.z * wi1[c].z + e.w * wi1[c].w;
            }
            #pragma unroll
            for (int m = 8; m >= 1; m >>= 1) {   // reduce over 16-lane group
                p0 += __shfl_xor(p0, m);
                p1 += __shfl_xor(p1, m);
            }
            if (sub == 0) s_pi[r] = make_float2(p0, p1);
        }
    }

    // proj_j: rows [r0-16, r0+80). 96 rows = 3 passes.
    for (int base = wv * 4; base < PJ_ROWS; base += NWAVES * 4) {
        const int r = base + g;
        const int row = hr0 + r;
        if (row >= 0 && row < n) {
            const float* ep = embeds_temp + (size_t)row * 256;
            float p0 = 0.f, p1 = 0.f;
            #pragma unroll
            for (int c = 0; c < 4; ++c) {
                const float4 e = *(const float4*)(ep + (c * 16 + sub) * 4);
                p0 += e.x * wj0[c].x + e.y * wj0[c].y + e.z * wj0[c].z + e.w * wj0[c].w;
                p1 += e.x * wj1[c].x + e.y * wj1[c].y + e.z * wj1[c].z + e.w * wj1[c].w;
            }
            #pragma unroll
            for (int m = 8; m >= 1; m >>= 1) {
                p0 += __shfl_xor(p0, m);
                p1 += __shfl_xor(p1, m);
            }
            if (sub == 0) s_pj[r] = make_float2(p0, p1);
        }
    }

    __syncthreads();

    // Gather this block's contiguous pair slice.
    const float b0 = bias[0], b1 = bias[1];
    const int plo = s_range[0], phi = s_range[1];
    for (int p = plo + tid; p < phi; p += NTHREADS) {
        const int i = idx_i[p];
        const int j = idx_j[p];
        const float2 a = s_pi[i - r0];
        const float2 c = s_pj[j - hr0];
        *(float2*)(out + 2 * (size_t)p) = make_float2(a.x + c.x + b0,
                                                      a.y + c.y + b1);
    }
}

extern "C" void kernel_launch(void* const* d_in, const int* in_sizes, int n_in,
                              void* d_out, int out_size, void* d_ws, size_t ws_size,
                              hipStream_t stream) {
    const float* embeds      = (const float*)d_in[0];
    const float* embeds_temp = (const float*)d_in[1];
    const float* weight      = (const float*)d_in[2];
    const float* bias        = (const float*)d_in[3];
    const int*   idx_i       = (const int*)d_in[4];
    const int*   idx_j       = (const int*)d_in[5];
    float* out = (float*)d_out;

    const int n      = in_sizes[0] / 256;   // rows
    const int npairs = in_sizes[4];         // pairs

    dim3 grid((n + R_ROWS - 1) / R_ROWS);   // 512 blocks for n=32768
    fused_senshift_kernel<<<grid, NTHREADS, 0, stream>>>(
        embeds, embeds_temp, weight, bias, idx_i, idx_j, out, n, npairs);
}